// Round 1
// 1570.332 us; speedup vs baseline: 2.4650x; 2.4650x over previous
//
#include <hip/hip_runtime.h>
#include <math.h>

namespace {
constexpr int B  = 16;
constexpr int H  = 8;
constexpr int HH = 4;
constexpr int N  = 1024;
constexpr int D  = 64;
constexpr int TQ = 16;                 // q rows per block (4 per wave)
constexpr int NT = N / 64;             // 16 K-tiles of 64 rows
constexpr float SCALE = 0.125f;        // 1/sqrt(64)
constexpr float LOG2E = 1.44269504088896340736f;
}

typedef __attribute__((address_space(3))) unsigned int lds_u32_t;
typedef __attribute__((address_space(1))) unsigned int glb_u32_t;

// 16B async global->LDS. LDS dest = wave-uniform base + lane*16 (linear).
__device__ __forceinline__ void gl_lds16(const float* g, float* l) {
    __builtin_amdgcn_global_load_lds((const glb_u32_t*)g, (lds_u32_t*)l, 16, 0, 0);
}

// R1 restructure:
//  - logits in registers e[4][16] (lane holds m = 64*t + lane), statically indexed
//  - K tiles staged to LDS via global_load_lds with pre-swizzled SOURCE address
//    (linear LDS dest), read back with the same XOR -> even 8-way b128 spread
//  - Q staged once to LDS, consumed as uniform broadcasts
//  - PV uses per-wave 4KB LDS chunks (no barriers) for w broadcast
//  - XCD swizzle: each XCD gets contiguous tiles of 2 (b,h) panels
__global__ __launch_bounds__(256, 4)
void bda_fused(const float* __restrict__ q, const float* __restrict__ k,
               const float* __restrict__ v, const float* __restrict__ sph,
               const float* __restrict__ hop, const float* __restrict__ gam,
               float* __restrict__ out, float* __restrict__ w)
{
    __shared__ __align__(16) float s_k[64 * 64];      // 16 KB staged K tile (xor-swizzled cols)
    __shared__ __align__(16) float s_q[TQ * 64];      // 4 KB Q tile (linear)
    __shared__ __align__(16) float s_ew[4][4][256];   // 16 KB: per-wave w chunk for PV broadcast

    // XCD-aware swizzle (8192 blocks, 8 XCDs, bijective: 8192 % 8 == 0)
    const int id   = (int)blockIdx.x;
    const int swz  = (id & 7) * 1024 + (id >> 3);
    const int tile = swz & 63;              // N/TQ = 64 tiles, fastest -> same panel stays on XCD
    const int h    = (swz >> 6) & 7;
    const int b    = swz >> 9;

    const int n0   = tile * TQ;
    const int tid  = (int)threadIdx.x;
    const int lane = tid & 63;
    const int wv   = tid >> 6;
    const int r0   = wv * 4;                // wave-owned rows n0+r0 .. n0+r0+3
    const long bh     = (long)b * H + h;
    const long kvbase = bh * N * D;

    const bool is_short = (h < HH);
    float l2g = 0.f, hopv = 0.f;
    if (is_short) {
        const float g = 1.0f / (1.0f + expf(-gam[h]));
        l2g  = log2f(g);
        hopv = hop[h];
    }

    // ---- stage Q tile (4 KB, linear, contiguous rows n0..n0+15) ----
    {
        const float* qg = q + kvbase + (long)n0 * D;
        gl_lds16(qg + wv * 256 + lane * 4, s_q + wv * 256);
    }

    const float* sp0 = sph + ((long)b * N + n0 + r0 + 0) * N;
    const float* sp1 = sph + ((long)b * N + n0 + r0 + 1) * N;
    const float* sp2 = sph + ((long)b * N + n0 + r0 + 2) * N;
    const float* sp3 = sph + ((long)b * N + n0 + r0 + 3) * N;

    float e[4][16];                        // logits -> exp -> normalized w, all in regs
    const float4* sq4 = (const float4*)s_q;
    const float4* sk4 = (const float4*)s_k;
    const float*  kg0 = k + kvbase;

    // ---- Phase 1: logits. lane owns column m = 64*t + lane of each row ----
    #pragma unroll
    for (int t = 0; t < NT; ++t) {
        __syncthreads();                   // previous tile fully consumed
        {   // stage K rows 64t..64t+63: linear LDS dest, swizzled global source.
            // LDS slot s=(m,c) holds k[m][4*(c^(m&15))..] -> read with same XOR.
            const float* kg = kg0 + (long)t * 64 * D;
            #pragma unroll
            for (int i = 0; i < 4; ++i) {
                const int s  = wv * 256 + i * 64 + lane;   // float4 slot index
                const int m  = s >> 4;
                const int cs = (s & 15) ^ (m & 15);
                gl_lds16(kg + m * D + cs * 4, s_k + (wv * 256 + i * 64) * 4);
            }
        }
        __syncthreads();                   // vmcnt(0) drained by compiler before barrier

        float a0 = 0.f, a1 = 0.f, a2 = 0.f, a3 = 0.f;
        #pragma unroll 2
        for (int d4 = 0; d4 < 16; ++d4) {
            const float4 kv4 = sk4[(lane << 4) + (d4 ^ (lane & 15))];  // k[64t+lane][4*d4..]
            float4 t4;
            t4 = sq4[(r0 + 0) * 16 + d4]; a0 += t4.x*kv4.x + t4.y*kv4.y + t4.z*kv4.z + t4.w*kv4.w;
            t4 = sq4[(r0 + 1) * 16 + d4]; a1 += t4.x*kv4.x + t4.y*kv4.y + t4.z*kv4.z + t4.w*kv4.w;
            t4 = sq4[(r0 + 2) * 16 + d4]; a2 += t4.x*kv4.x + t4.y*kv4.y + t4.z*kv4.z + t4.w*kv4.w;
            t4 = sq4[(r0 + 3) * 16 + d4]; a3 += t4.x*kv4.x + t4.y*kv4.y + t4.z*kv4.z + t4.w*kv4.w;
        }
        a0 *= SCALE; a1 *= SCALE; a2 *= SCALE; a3 *= SCALE;
        if (is_short) {
            const int mo = t * 64 + lane;
            a0 *= exp2f(l2g * fmaxf(sp0[mo] - hopv, 0.f));
            a1 *= exp2f(l2g * fmaxf(sp1[mo] - hopv, 0.f));
            a2 *= exp2f(l2g * fmaxf(sp2[mo] - hopv, 0.f));
            a3 *= exp2f(l2g * fmaxf(sp3[mo] - hopv, 0.f));
        }
        e[0][t] = a0; e[1][t] = a1; e[2][t] = a2; e[3][t] = a3;
    }

    // ---- Phase 2: softmax per row, fully in regs + 64-lane shuffles; write w ----
    float* wbase = w + (bh * N + n0 + r0) * (long)N;
    #pragma unroll
    for (int r = 0; r < 4; ++r) {
        float mx = e[r][0];
        #pragma unroll
        for (int t = 1; t < 16; ++t) mx = fmaxf(mx, e[r][t]);
        #pragma unroll
        for (int off = 32; off; off >>= 1) mx = fmaxf(mx, __shfl_xor(mx, off));
        float sm = 0.f;
        #pragma unroll
        for (int t = 0; t < 16; ++t) {
            const float ev = exp2f((e[r][t] - mx) * LOG2E);
            e[r][t] = ev; sm += ev;
        }
        #pragma unroll
        for (int off = 32; off; off >>= 1) sm += __shfl_xor(sm, off);
        const float iv = 1.0f / sm;
        float* wrow = wbase + (long)r * N;
        #pragma unroll
        for (int t = 0; t < 16; ++t) {
            const float wv_ = e[r][t] * iv;   // e becomes the final normalized weight
            e[r][t] = wv_;
            wrow[t * 64 + lane] = wv_;        // coalesced 256B stores
        }
    }

    // ---- Phase 3: PV. 4 chunks of 256 m; per-wave LDS broadcast, no barriers ----
    const float* vb = v + kvbase;
    float o0 = 0.f, o1 = 0.f, o2 = 0.f, o3 = 0.f;
    #pragma unroll
    for (int c = 0; c < 4; ++c) {
        #pragma unroll
        for (int j = 0; j < 4; ++j) {         // m = 256c + 64j + lane
            s_ew[wv][0][j * 64 + lane] = e[0][c * 4 + j];
            s_ew[wv][1][j * 64 + lane] = e[1][c * 4 + j];
            s_ew[wv][2][j * 64 + lane] = e[2][c * 4 + j];
            s_ew[wv][3][j * 64 + lane] = e[3][c * 4 + j];
        }
        const float* vc = vb + (long)c * 256 * D;
        for (int m4 = 0; m4 < 64; ++m4) {
            const int m = m4 * 4;
            const float4 E0 = *(const float4*)&s_ew[wv][0][m];   // uniform b128 broadcast
            const float4 E1 = *(const float4*)&s_ew[wv][1][m];
            const float4 E2 = *(const float4*)&s_ew[wv][2][m];
            const float4 E3 = *(const float4*)&s_ew[wv][3][m];
            const float v0_ = vc[(m + 0) * D + lane];            // coalesced 256B loads
            const float v1_ = vc[(m + 1) * D + lane];
            const float v2_ = vc[(m + 2) * D + lane];
            const float v3_ = vc[(m + 3) * D + lane];
            o0 += E0.x*v0_ + E0.y*v1_ + E0.z*v2_ + E0.w*v3_;
            o1 += E1.x*v0_ + E1.y*v1_ + E1.z*v2_ + E1.w*v3_;
            o2 += E2.x*v0_ + E2.y*v1_ + E2.z*v2_ + E2.w*v3_;
            o3 += E3.x*v0_ + E3.y*v1_ + E3.z*v2_ + E3.w*v3_;
        }
    }
    const long ob = (bh * N + n0 + r0) * (long)D + lane;
    out[ob + 0 * D] = o0;                     // already normalized (e held w)
    out[ob + 1 * D] = o1;
    out[ob + 2 * D] = o2;
    out[ob + 3 * D] = o3;
}

extern "C" void kernel_launch(void* const* d_in, const int* in_sizes, int n_in,
                              void* d_out, int out_size, void* d_ws, size_t ws_size,
                              hipStream_t stream) {
    const float* q   = (const float*)d_in[0];
    const float* k   = (const float*)d_in[1];
    const float* v   = (const float*)d_in[2];
    const float* sph = (const float*)d_in[3];
    const float* hop = (const float*)d_in[4];
    const float* gam = (const float*)d_in[5];

    float* out = (float*)d_out;                       // (B,H,N,D)
    float* w   = out + (size_t)B * H * N * D;         // (B,H,N,N)

    dim3 grid(B * H * (N / TQ));                      // 8192 blocks, XCD-swizzled in-kernel
    bda_fused<<<grid, 256, 0, stream>>>(q, k, v, sph, hop, gam, out, w);
}